// Round 3
// baseline (4356.837 us; speedup 1.0000x reference)
//
#include <hip/hip_runtime.h>
#include <cstdint>
#include <cstddef>

// Round 3: dtype-adaptive correctness baseline. All compute in f32 VALU.
// A detector kernel decides at runtime whether d_in buffers are bf16 or f32;
// all global loads of inputs go through ldu(ptr, i, flag). Output written in
// the detected dtype. B=8, SL=1024, D=128, E=4, STEPS=5.

typedef unsigned short u16;
typedef unsigned int u32;
typedef float f32x4 __attribute__((ext_vector_type(4)));

__device__ __forceinline__ float b2f(u16 h) {
  union { u32 u; float f; } v; v.u = ((u32)h) << 16; return v.f;
}
__device__ __forceinline__ u16 f2bf(float f) {
  union { float f; u32 u; } v; v.f = f;
  u32 r = (v.u + 0x7fffu + ((v.u >> 16) & 1u)) >> 16;
  return (u16)r;
}
__device__ __forceinline__ float ldu(const void* p, size_t i, int flag) {
  return flag ? ((const float*)p)[i] : b2f(((const u16*)p)[i]);
}

// ---- detect input dtype from batchgraphin bit patterns.
// bf16 U[0,1/1024] values: every u16 <= 0x3A83. f32: interleaved mantissa
// words are ~uniform over 64K -> some u16 > 0x3B00 with certainty.
__global__ void k_detect(const u16* g, int* flag) {
  __shared__ int bad;
  if (threadIdx.x == 0) bad = 0;
  __syncthreads();
  int any = 0;
  for (int i = threadIdx.x; i < 8192; i += 256) any |= (g[i] > 0x3B00);
  if (any) atomicOr(&bad, 1);
  __syncthreads();
  if (threadIdx.x == 0) *flag = bad;   // 1 => inputs are f32
}

// ---- generic convert-to-f32
__global__ void k_cvtf(const void* src, float* dst, int n, const int* flagp) {
  int i = blockIdx.x * 256 + threadIdx.x;
  if (i < n) dst[i] = ldu(src, i, *flagp);
}

// ---- weffT[k][j] = sum_e Wcat[j][e*128+k]; biasf = [b_in | b_out] (f32)
__global__ void k_weff(const void* Win, const void* bin, const void* Wout, const void* bout,
                       float* weffT, float* biasf, const int* flagp) {
  int flag = *flagp;
  int idx = blockIdx.x * 256 + threadIdx.x;   // 131072
  int j = idx >> 7, k = idx & 127;
  float s = 0.f;
  if (j < 512) {
#pragma unroll
    for (int e = 0; e < 4; e++) s += ldu(Win, (size_t)j * 512 + e * 128 + k, flag);
  } else {
#pragma unroll
    for (int e = 0; e < 4; e++) s += ldu(Wout, (size_t)(j - 512) * 512 + e * 128 + k, flag);
  }
  weffT[k * 1024 + j] = s;
  if (idx < 1024) biasf[idx] = (idx < 512) ? ldu(bin, idx, flag) : ldu(bout, idx - 512, flag);
}

// ---- WT[k][n] = W[n][k] for the 128x384 gate weights; bias to f32.
__global__ void k_wt(const void* W, const void* bv, float* WT, float* bf, const int* flagp) {
  int flag = *flagp;
  int idx = blockIdx.x * 256 + threadIdx.x;   // 49152
  int n = idx / 384, k = idx % 384;
  WT[k * 128 + n] = ldu(W, idx, flag);
  if (idx < 128) bf[idx] = ldu(bv, idx, flag);
}

// ---- gpre[(gate*8+b)*4096 + s*4+e][d] = Weff[j]·out[m] + bias[j], j=gate*512+e*128+d
__global__ __launch_bounds__(256, 2) void kg_pre(const float* __restrict__ weffT,
                                                 const float* __restrict__ biasf,
                                                 const float* __restrict__ outF,
                                                 float* __restrict__ gpre) {
  __shared__ __align__(16) float xs[32 * 128];
  int t = threadIdx.x;
  int gb = blockIdx.y, gate = gb >> 3, b = gb & 7;
  int s0 = blockIdx.x * 32;
  for (int idx = t; idx < 4096; idx += 256)
    xs[idx] = outF[(size_t)(b * 1024 + s0 + (idx >> 7)) * 128 + (idx & 127)];
  __syncthreads();
  int d = t & 127, eh = t >> 7;
  int j0 = gate * 512 + (eh * 2) * 128 + d;
  float acc0[32] = {}, acc1[32] = {};
  for (int k = 0; k < 128; k++) {
    float w0 = weffT[k * 1024 + j0];
    float w1 = weffT[k * 1024 + j0 + 128];
#pragma unroll
    for (int s = 0; s < 32; s++) {
      float x = xs[s * 128 + k];
      acc0[s] += x * w0;
      acc1[s] += x * w1;
    }
  }
  float bj0 = biasf[j0], bj1 = biasf[j0 + 128];
  size_t base = (size_t)(gate * 8 + b) * 4096;
  for (int s = 0; s < 32; s++) {
    size_t row = base + (size_t)(s0 + s) * 4;
    gpre[(row + eh * 2)     * 128 + d] = acc0[s] + bj0;
    gpre[(row + eh * 2 + 1) * 128 + d] = acc1[s] + bj1;
  }
}

// ---- bmm: catF[m][gate*128+d] = sum_k graph[b][s][k] * gpre[(gate,b)][k][d]
__global__ __launch_bounds__(256, 2) void kg_bmm(const void* __restrict__ gin,
                                                 const void* __restrict__ gout,
                                                 const float* __restrict__ gpre,
                                                 float* __restrict__ catF,
                                                 const int* __restrict__ flagp) {
  __shared__ __align__(16) float gt[32][36];    // graph tile [s][k], padded
  __shared__ __align__(16) float gs[32 * 128];  // gpre tile [k][d]
  int flag = *flagp;
  int t = threadIdx.x;
  int gb = blockIdx.y, gate = gb >> 3, b = gb & 7;
  int s0 = blockIdx.x * 32;
  const void* G = gate ? gout : gin;
  size_t gbase = (size_t)b * 1024 * 4096;
  const float* gp = gpre + (size_t)(gate * 8 + b) * 4096 * 128;
  int d4 = t & 31, sg = t >> 5;
  f32x4 acc4[4] = {};
  for (int kt = 0; kt < 128; kt++) {
    int k0 = kt * 32;
    __syncthreads();
    for (int idx = t; idx < 1024; idx += 256)
      gt[idx >> 5][idx & 31] = ldu(G, gbase + (size_t)(s0 + (idx >> 5)) * 4096 + k0 + (idx & 31), flag);
    for (int idx = t; idx < 4096; idx += 256)
      gs[idx] = gp[(size_t)(k0 + (idx >> 7)) * 128 + (idx & 127)];
    __syncthreads();
#pragma unroll
    for (int kq = 0; kq < 8; kq++) {
      f32x4 gv[4], pv[4];
#pragma unroll
      for (int si = 0; si < 4; si++) gv[si] = *(const f32x4*)&gt[sg * 4 + si][kq * 4];
#pragma unroll
      for (int kl = 0; kl < 4; kl++) pv[kl] = *(const f32x4*)&gs[(kq * 4 + kl) * 128 + d4 * 4];
#pragma unroll
      for (int si = 0; si < 4; si++)
#pragma unroll
        for (int kl = 0; kl < 4; kl++)
          acc4[si] += gv[si][kl] * pv[kl];
    }
  }
#pragma unroll
  for (int si = 0; si < 4; si++) {
    int s = s0 + sg * 4 + si;
    *(f32x4*)&catF[(size_t)(b * 1024 + s) * 384 + gate * 128 + d4 * 4] = acc4[si];
  }
}

// ---- copy state into cat slice 2
__global__ void k_scpy(const float* __restrict__ outF, float* __restrict__ catF) {
  int i = blockIdx.x * 256 + threadIdx.x;  // 1048576
  catF[(size_t)(i >> 7) * 384 + 256 + (i & 127)] = outF[i];
}

// ---- r,z gates: rp = sigmoid(cat@Wr^T+br)*out ; zf = sigmoid(cat@Wz^T+bz)
__global__ __launch_bounds__(256, 2) void kg_rz(const float* __restrict__ catF,
                                                const float* __restrict__ WTr,
                                                const float* __restrict__ WTz,
                                                const float* __restrict__ brf,
                                                const float* __restrict__ bzf,
                                                const float* __restrict__ outF,
                                                float* __restrict__ rp, float* __restrict__ zf) {
  __shared__ __align__(16) float cs[16 * 384];
  int t = threadIdx.x;
  int m0 = blockIdx.x * 16;
  for (int idx = t; idx < 6144; idx += 256)
    cs[idx] = catF[(size_t)(m0 + idx / 384) * 384 + idx % 384];
  __syncthreads();
  int n = t & 127, mh = t >> 7;
  float accR[8] = {}, accZ[8] = {};
  for (int kq = 0; kq < 96; kq++) {
    float wr[4], wz[4];
#pragma unroll
    for (int kl = 0; kl < 4; kl++) {
      wr[kl] = WTr[(kq * 4 + kl) * 128 + n];
      wz[kl] = WTz[(kq * 4 + kl) * 128 + n];
    }
#pragma unroll
    for (int mi = 0; mi < 8; mi++) {
      f32x4 c = *(const f32x4*)&cs[(mh * 8 + mi) * 384 + kq * 4];
#pragma unroll
      for (int kl = 0; kl < 4; kl++) { accR[mi] += c[kl] * wr[kl]; accZ[mi] += c[kl] * wz[kl]; }
    }
  }
  float bR = brf[n], bZ = bzf[n];
#pragma unroll
  for (int mi = 0; mi < 8; mi++) {
    int m = m0 + mh * 8 + mi;
    size_t o = (size_t)m * 128 + n;
    float r = 1.f / (1.f + __expf(-(accR[mi] + bR)));
    float z = 1.f / (1.f + __expf(-(accZ[mi] + bZ)));
    rp[o] = r * outF[o];
    zf[o] = z;
  }
}

// ---- h gate + state update (+ final output in detected dtype)
__global__ __launch_bounds__(256, 2) void kg_h(const float* __restrict__ catF,
                                               const float* __restrict__ rp,
                                               const float* __restrict__ WTt,
                                               const float* __restrict__ btf,
                                               const float* __restrict__ zf,
                                               float* __restrict__ outF,
                                               const int* __restrict__ flagp,
                                               void* __restrict__ dout, int writeOut) {
  __shared__ __align__(16) float cs[16 * 384];
  int t = threadIdx.x;
  int m0 = blockIdx.x * 16;
  for (int idx = t; idx < 6144; idx += 256) {
    int r = idx / 384, k = idx % 384;
    cs[idx] = (k < 256) ? catF[(size_t)(m0 + r) * 384 + k]
                        : rp[(size_t)(m0 + r) * 128 + (k - 256)];
  }
  __syncthreads();
  int n = t & 127, mh = t >> 7;
  float acc[8] = {};
  for (int kq = 0; kq < 96; kq++) {
    float wt[4];
#pragma unroll
    for (int kl = 0; kl < 4; kl++) wt[kl] = WTt[(kq * 4 + kl) * 128 + n];
#pragma unroll
    for (int mi = 0; mi < 8; mi++) {
      f32x4 c = *(const f32x4*)&cs[(mh * 8 + mi) * 384 + kq * 4];
#pragma unroll
      for (int kl = 0; kl < 4; kl++) acc[mi] += c[kl] * wt[kl];
    }
  }
  float bT = btf[n];
  int flag = *flagp;
#pragma unroll
  for (int mi = 0; mi < 8; mi++) {
    int m = m0 + mh * 8 + mi;
    size_t o = (size_t)m * 128 + n;
    float h = tanhf(acc[mi] + bT);
    float z = zf[o];
    float res = (1.f - z) * outF[o] + z * h;
    outF[o] = res;
    if (writeOut) {
      if (flag) ((float*)dout)[o] = res;
      else      ((u16*)dout)[o] = f2bf(res);
    }
  }
}

extern "C" void kernel_launch(void* const* d_in, const int* in_sizes, int n_in,
                              void* d_out, int out_size, void* d_ws, size_t ws_size,
                              hipStream_t stream) {
  const void* X    = d_in[0];
  const void* Gin  = d_in[1];
  const void* Gout = d_in[2];
  const void* Win  = d_in[3];
  const void* bin  = d_in[4];
  const void* Wout = d_in[5];
  const void* bout = d_in[6];
  const void* Wr   = d_in[7];
  const void* br   = d_in[8];
  const void* Wz   = d_in[9];
  const void* bz   = d_in[10];
  const void* Wt   = d_in[11];
  const void* bt   = d_in[12];

  char* w = (char*)d_ws;
  auto alloc = [&](size_t n) { char* p = w; w += (n + 255) & ~(size_t)255; return p; };
  int*   flag  = (int*)alloc(4);
  float* weffT = (float*)alloc((size_t)128 * 1024 * 4);            // 512 KB
  float* biasf = (float*)alloc(1024 * 4);
  float* WTr   = (float*)alloc((size_t)384 * 128 * 4);
  float* WTz   = (float*)alloc((size_t)384 * 128 * 4);
  float* WTt   = (float*)alloc((size_t)384 * 128 * 4);
  float* brf   = (float*)alloc(128 * 4);
  float* bzf   = (float*)alloc(128 * 4);
  float* btf   = (float*)alloc(128 * 4);
  float* outF  = (float*)alloc((size_t)8192 * 128 * 4);            // 4 MB
  float* gpre  = (float*)alloc((size_t)16 * 4096 * 128 * 4);       // 32 MB
  float* catF  = (float*)alloc((size_t)8192 * 384 * 4);            // 12 MB
  float* rp    = (float*)alloc((size_t)8192 * 128 * 4);            // 4 MB
  float* zf    = (float*)alloc((size_t)8192 * 128 * 4);            // 4 MB
  (void)ws_size; (void)in_sizes; (void)n_in; (void)out_size;

  k_detect<<<1, 256, 0, stream>>>((const u16*)Gin, flag);
  k_weff<<<512, 256, 0, stream>>>(Win, bin, Wout, bout, weffT, biasf, flag);
  k_wt<<<192, 256, 0, stream>>>(Wr, br, WTr, brf, flag);
  k_wt<<<192, 256, 0, stream>>>(Wz, bz, WTz, bzf, flag);
  k_wt<<<192, 256, 0, stream>>>(Wt, bt, WTt, btf, flag);
  k_cvtf<<<4096, 256, 0, stream>>>(X, outF, 1048576, flag);

  for (int step = 0; step < 5; step++) {
    kg_pre<<<dim3(32, 16), 256, 0, stream>>>(weffT, biasf, outF, gpre);
    kg_bmm<<<dim3(32, 16), 256, 0, stream>>>(Gin, Gout, gpre, catF, flag);
    k_scpy<<<4096, 256, 0, stream>>>(outF, catF);
    kg_rz<<<512, 256, 0, stream>>>(catF, WTr, WTz, brf, bzf, outF, rp, zf);
    kg_h<<<512, 256, 0, stream>>>(catF, rp, WTt, btf, zf, outF, flag, d_out,
                                  (step == 4) ? 1 : 0);
  }
}